// Round 8
// baseline (353.271 us; speedup 1.0000x reference)
//
#include <hip/hip_runtime.h>
#include <hip/hip_bf16.h>

// TransformerBlock fused kernel for MI355X (gfx950) — v7: 2 blocks/CU.
// Shapes: B=1024, T=128, D=128, H=4, HD=32, FF=512.
// One block per batch element; 512 threads = 8 waves. LDS 69,632 B -> 2 blocks/CU.
//
// v6.1 post-mortem: 217 us at 22.7% occupancy; ~60% latency stalls at
// 2 waves/SIMD. v7 keeps v6.1's per-block pipeline but shrinks LDS to TWO
// 128x136 tiles (K and Vt) so two blocks co-reside:
//  - LN1 in registers (row-local): each wave normalizes its own 16 rows into
//    hf[4] B-frags; hs tile + P0 phase + 1 barrier deleted.
//  - P1 iterates WEIGHT tiles against the fixed hf frags (same 96 MFMAs);
//    weights pre-converted to bf16 into d_ws by a prep kernel (no cvt VALU,
//    half the weight bytes, L2-resident).
//  - Q: one quad_collect_pk (verified in v3/v4) -> 4 persistent B-frags; no Q tile.
//  - P: quad_collect_pk -> PV A..B-frags in-register; no P tile, no rule-18 fence.
//  - attn_h overwrites K's head-h columns in place (barrier per head after all
//    S_h reads); x1 reuses Vt tile; h2 reuses K tile; G single-buffers Vt tile.
// MFMA totals unchanged (448/wave). __launch_bounds__(512,2): proven no-spill;
// residency then resource-determined (needs VGPR<=128 for 2 blocks).
// MFMA 16x16x32 bf16. A-frag: A[m=lane&15][k=quad*8+j]; B-frag:
// B[k=quad*8+j][n=lane&15]; C/D: col=lane&15, row=quad*4+reg (learn_hip m89/m91).

typedef short bf16x8 __attribute__((ext_vector_type(8)));   // 8 bf16 in 4 VGPRs
typedef float f32x4  __attribute__((ext_vector_type(4)));
typedef unsigned short u16;
typedef unsigned int   u32;

#define TT   128
#define DDIM 128
#define FFD  512
#define PIT  136   // LDS row pitch (bf16): 272 B -> rows 16B-aligned

// ws layout (u16 element offsets) for bf16 weight copies
#define OWQ 0
#define OWK 16384
#define OWV 32768
#define OWO 49152
#define OW1 65536
#define OW2 131072
#define WTOT 196608

// SCALE * log2(e): softmax in exp2 domain, folded into Q. SCALE = 128^-0.5.
#define QSC 0.12751744f

#if defined(__has_builtin)
#if __has_builtin(__builtin_amdgcn_exp2f)
#define EXP2F(x) __builtin_amdgcn_exp2f(x)
#else
#define EXP2F(x) exp2f(x)
#endif
#else
#define EXP2F(x) exp2f(x)
#endif

__device__ __forceinline__ u16 f2b(float f) {
    __hip_bfloat16 h = __float2bfloat16(f);   // RNE
    return __builtin_bit_cast(u16, h);
}
__device__ __forceinline__ u32 pk2(float x, float y) {
    return (u32)f2b(x) | ((u32)f2b(y) << 16);
}
__device__ __forceinline__ void st_b64(u16* p, u32 lo, u32 hi) {  // 8B-aligned
    uint2 v; v.x = lo; v.y = hi;
    *reinterpret_cast<uint2*>(p) = v;
}
__device__ __forceinline__ bf16x8 ldfrag(const u16* p) {  // LDS/global, 16B-aligned
    return __builtin_bit_cast(bf16x8, *reinterpret_cast<const uint4*>(p));
}
__device__ __forceinline__ f32x4 mfma16(bf16x8 a, bf16x8 b, f32x4 c) {
    return __builtin_amdgcn_mfma_f32_16x16x32_bf16(a, b, c, 0, 0, 0);
}

// Cross-quad repack (verified in v3/v4 runs): pkv[i][d0] =
// pack(V[row][i*16+quad*4+2*d0], V[row][i*16+quad*4+2*d0+1]) (C-layout columns
// of this lane's row); output fr[g][j] = bf16(V[row][g*32+quad*8+j]) (A/B-frag).
__device__ __forceinline__ void quad_collect_pk(const u32 (&pkv)[8][2],
                                                bf16x8 (&fr)[4], int lane) {
    const int srcA = (lane & 15) + ((lane & 16) << 1);  // lq + 32*l4'
    const int srcB = srcA + 16;
    const bool hi = (lane & 32) != 0;                   // l5'
    #pragma unroll
    for (int g = 0; g < 4; g++) {
        u32 D00 = pkv[2*g][0],     D01 = pkv[2*g][1];
        u32 D10 = pkv[2*g + 1][0], D11 = pkv[2*g + 1][1];
        u32 a00 = (u32)__shfl((int)D00, srcA);
        u32 a10 = (u32)__shfl((int)D10, srcA);
        u32 a01 = (u32)__shfl((int)D01, srcA);
        u32 a11 = (u32)__shfl((int)D11, srcA);
        u32 b00 = (u32)__shfl((int)D00, srcB);
        u32 b10 = (u32)__shfl((int)D10, srcB);
        u32 b01 = (u32)__shfl((int)D01, srcB);
        u32 b11 = (u32)__shfl((int)D11, srcB);
        uint4 q;
        q.x = hi ? a10 : a00;
        q.y = hi ? a11 : a01;
        q.z = hi ? b10 : b00;
        q.w = hi ? b11 : b01;
        fr[g] = __builtin_bit_cast(bf16x8, q);
    }
}

// Weight prep: f32 -> bf16 copies into workspace (runs once per launch, ~3 us).
__global__ __launch_bounds__(256) void wprep(
    const float* __restrict__ wq, const float* __restrict__ wk,
    const float* __restrict__ wv, const float* __restrict__ wo,
    const float* __restrict__ w1, const float* __restrict__ w2,
    u16* __restrict__ dst)
{
    int i = (blockIdx.x * 256 + threadIdx.x) * 8;
    if (i >= WTOT) return;
    const float* s; int off;
    if      (i < OWK) { s = wq; off = i - OWQ; }
    else if (i < OWV) { s = wk; off = i - OWK; }
    else if (i < OWO) { s = wv; off = i - OWV; }
    else if (i < OW1) { s = wo; off = i - OWO; }
    else if (i < OW2) { s = w1; off = i - OW1; }
    else              { s = w2; off = i - OW2; }
    float4 a = *reinterpret_cast<const float4*>(s + off);
    float4 b = *reinterpret_cast<const float4*>(s + off + 4);
    uint4 o;
    o.x = pk2(a.x, a.y); o.y = pk2(a.z, a.w);
    o.z = pk2(b.x, b.y); o.w = pk2(b.z, b.w);
    *reinterpret_cast<uint4*>(dst + i) = o;
}

__global__ __launch_bounds__(512, 2) void tblock_kernel(
    const float* __restrict__ x,
    const float* __restrict__ ln1g, const float* __restrict__ ln1b,
    const u16*  __restrict__ wbf,
    const float* __restrict__ bo,
    const float* __restrict__ ln2g, const float* __restrict__ ln2b,
    const float* __restrict__ b1,   const float* __restrict__ b2,
    float* __restrict__ out)
{
    // 69,632 B total, two [128][136] bf16 tiles:
    //   bufK: K[t][dout] -> attn[t][dout] (per-head in-place) -> h2[t][d]
    //   bufV: Vt[o][t]   -> x1[t][d]      -> G[t][f] (single-buffered)
    __shared__ __align__(16) u16 sm[2 * TT * PIT];
    u16* bufK = sm;
    u16* bufV = sm + TT * PIT;

    const int b    = blockIdx.x;
    const int tid  = threadIdx.x;
    const int w    = tid >> 6;     // wave id 0..7
    const int l    = tid & 63;
    const int lq   = l & 15;
    const int quad = l >> 4;
    const int trow = w * 16 + lq;  // this lane's token row
    const float* xb = x + (size_t)b * (TT * DDIM);

    const u16* wq = wbf + OWQ;
    const u16* wk = wbf + OWK;
    const u16* wv = wbf + OWV;
    const u16* wo = wbf + OWO;
    const u16* w1 = wbf + OW1;
    const u16* w2 = wbf + OW2;

    // ---------------- LN1 in registers (own row) -> hf[4] B-frags ----------
    bf16x8 hf[4];
    {
        float v[32];
        float s = 0.f, s2 = 0.f;
        #pragma unroll
        for (int ks = 0; ks < 4; ks++) {
            const float* src = xb + trow * DDIM + ks * 32 + quad * 8;
            float4 u0 = *reinterpret_cast<const float4*>(src);
            float4 u1 = *reinterpret_cast<const float4*>(src + 4);
            v[ks*8+0]=u0.x; v[ks*8+1]=u0.y; v[ks*8+2]=u0.z; v[ks*8+3]=u0.w;
            v[ks*8+4]=u1.x; v[ks*8+5]=u1.y; v[ks*8+6]=u1.z; v[ks*8+7]=u1.w;
            s  += u0.x+u0.y+u0.z+u0.w + u1.x+u1.y+u1.z+u1.w;
            s2 += u0.x*u0.x+u0.y*u0.y+u0.z*u0.z+u0.w*u0.w
                + u1.x*u1.x+u1.y*u1.y+u1.z*u1.z+u1.w*u1.w;
        }
        // full row spans the 4 quads of lanes with equal lq
        s  += __shfl_xor(s, 16);  s2 += __shfl_xor(s2, 16);
        s  += __shfl_xor(s, 32);  s2 += __shfl_xor(s2, 32);
        float mean = s * (1.f / 128.f);
        float var  = fmaxf(s2 * (1.f / 128.f) - mean * mean, 0.f);
        float rstd = rsqrtf(var + 1e-5f);
        #pragma unroll
        for (int ks = 0; ks < 4; ks++) {
            const float* gp = ln1g + ks * 32 + quad * 8;
            const float* bp = ln1b + ks * 32 + quad * 8;
            float4 g0 = *reinterpret_cast<const float4*>(gp);
            float4 g1 = *reinterpret_cast<const float4*>(gp + 4);
            float4 c0 = *reinterpret_cast<const float4*>(bp);
            float4 c1 = *reinterpret_cast<const float4*>(bp + 4);
            float gg[8] = {g0.x,g0.y,g0.z,g0.w,g1.x,g1.y,g1.z,g1.w};
            float bb[8] = {c0.x,c0.y,c0.z,c0.w,c1.x,c1.y,c1.z,c1.w};
            #pragma unroll
            for (int j = 0; j < 8; j++)
                hf[ks][j] = (short)f2b((v[ks*8+j] - mean) * rstd * gg[j] + bb[j]);
        }
    }

    // ---------------- P1: K -> bufK (b64), Q -> regs, Vt -> bufV -----------
    // Weight-tile iteration against fixed hf (B = own t-tile).
    #pragma unroll
    for (int mt = 0; mt < 8; mt++) {
        f32x4 acc = {0, 0, 0, 0};
        #pragma unroll
        for (int ks = 0; ks < 4; ks++) {
            bf16x8 aw = ldfrag(wk + (mt * 16 + lq) * DDIM + ks * 32 + quad * 8);
            acc = mfma16(aw, hf[ks], acc);
        }
        st_b64(bufK + trow * PIT + mt * 16 + quad * 4,
               pk2(acc[0], acc[1]), pk2(acc[2], acc[3]));
    }
    bf16x8 qf[4];   // per-head Q B-frags (head g = frag g), persist through P2
    {
        u32 qpk[8][2];
        #pragma unroll
        for (int mt = 0; mt < 8; mt++) {
            f32x4 acc = {0, 0, 0, 0};
            #pragma unroll
            for (int ks = 0; ks < 4; ks++) {
                bf16x8 aw = ldfrag(wq + (mt * 16 + lq) * DDIM + ks * 32 + quad * 8);
                acc = mfma16(aw, hf[ks], acc);
            }
            qpk[mt][0] = pk2(acc[0] * QSC, acc[1] * QSC);
            qpk[mt][1] = pk2(acc[2] * QSC, acc[3] * QSC);
        }
        quad_collect_pk(qpk, qf, l);
    }
    #pragma unroll
    for (int mt = 0; mt < 8; mt++) {
        f32x4 acc = {0, 0, 0, 0};
        #pragma unroll
        for (int ks = 0; ks < 4; ks++) {
            bf16x8 av = ldfrag(wv + (mt * 16 + lq) * DDIM + ks * 32 + quad * 8);
            acc = mfma16(av, hf[ks], acc);
        }
        #pragma unroll
        for (int r = 0; r < 4; r++)
            bufV[(mt * 16 + quad * 4 + r) * PIT + trow] = f2b(acc[r]);
    }
    __syncthreads();

    // ---------------- P2: attention; attn_h overwrites K cols h ------------
    #pragma unroll
    for (int h = 0; h < 4; h++) {
        // S^T = mfma(K-frag, Q-frag): lane holds S[trow][s=n*16+quad*4+r]
        float p[8][4];
        #pragma unroll
        for (int n = 0; n < 8; n++) {
            bf16x8 ka = ldfrag(bufK + (n * 16 + lq) * PIT + h * 32 + quad * 8);
            f32x4 s4 = mfma16(ka, qf[h], f32x4{0, 0, 0, 0});
            #pragma unroll
            for (int r = 0; r < 4; r++) p[n][r] = s4[r];
        }
        __syncthreads();   // ALL waves' S_h reads done -> K cols h writable
        // causal softmax (exp2 domain, scale pre-folded into Q, norm deferred)
        float mx = -3.0e38f;
        #pragma unroll
        for (int n = 0; n < 8; n++) {
            #pragma unroll
            for (int r = 0; r < 4; r++) {
                int sc = n * 16 + quad * 4 + r;
                mx = (sc <= trow) ? fmaxf(mx, p[n][r]) : mx;
            }
        }
        mx = fmaxf(mx, __shfl_xor(mx, 16));
        mx = fmaxf(mx, __shfl_xor(mx, 32));   // full-row max
        float sum = 0.f;
        u32 ppk[8][2];   // unnormalized exp, packed bf16 pairs
        #pragma unroll
        for (int n = 0; n < 8; n++) {
            float e0, e1, e2, e3;
            {
                int sc = n * 16 + quad * 4;
                e0 = (sc     <= trow) ? EXP2F(p[n][0] - mx) : 0.f;
                e1 = (sc + 1 <= trow) ? EXP2F(p[n][1] - mx) : 0.f;
                e2 = (sc + 2 <= trow) ? EXP2F(p[n][2] - mx) : 0.f;
                e3 = (sc + 3 <= trow) ? EXP2F(p[n][3] - mx) : 0.f;
            }
            sum += e0 + e1 + e2 + e3;
            ppk[n][0] = pk2(e0, e1);
            ppk[n][1] = pk2(e2, e3);
        }
        sum += __shfl_xor(sum, 16);
        sum += __shfl_xor(sum, 32);           // full-row sum
        float inv = 1.f / sum;   // sum >= 1 (max entry contributes exp2(0)=1)
        // P -> A/B-frags fully in-register
        bf16x8 pfr[4];
        quad_collect_pk(ppk, pfr, l);
        // Swapped PV: attn^T = mfma(A=Vt, B=P); output t = trow lane-local
        f32x4 o0 = {0, 0, 0, 0}, o1 = {0, 0, 0, 0};
        #pragma unroll
        for (int ks = 0; ks < 4; ks++) {
            bf16x8 va0 = ldfrag(bufV + (h * 32 + lq) * PIT + ks * 32 + quad * 8);
            bf16x8 va1 = ldfrag(bufV + (h * 32 + 16 + lq) * PIT + ks * 32 + quad * 8);
            o0 = mfma16(va0, pfr[ks], o0);
            o1 = mfma16(va1, pfr[ks], o1);
        }
        #pragma unroll
        for (int r = 0; r < 4; r++) { o0[r] *= inv; o1[r] *= inv; }
        // attn_h into K's head-h columns (dead after this head's barrier)
        st_b64(bufK + trow * PIT + h * 32 + quad * 4,
               pk2(o0[0], o0[1]), pk2(o0[2], o0[3]));
        st_b64(bufK + trow * PIT + h * 32 + 16 + quad * 4,
               pk2(o1[0], o1[1]), pk2(o1[2], o1[3]));
    }
    __syncthreads();   // attn tile complete (bufK); Vt fully consumed

    // ---------------- P3: x1 = x + attn @ Wo^T + bo -> bufV + regs ---------
    float x1res[8][4];
    {
        bf16x8 woa[4];
        #pragma unroll
        for (int ks = 0; ks < 4; ks++)
            woa[ks] = ldfrag(wo + (w * 16 + lq) * DDIM + ks * 32 + quad * 8);
        const float4 bo4 = *reinterpret_cast<const float4*>(bo + w * 16 + quad * 4);
        #pragma unroll
        for (int m = 0; m < 8; m++) {
            f32x4 acc = {0, 0, 0, 0};
            #pragma unroll
            for (int ks = 0; ks < 4; ks++) {
                bf16x8 ab = ldfrag(bufK + (m * 16 + lq) * PIT + ks * 32 + quad * 8);
                acc = mfma16(woa[ks], ab, acc);
            }
            int t = m * 16 + lq;
            const float4 xv = *reinterpret_cast<const float4*>(xb + t * DDIM + w * 16 + quad * 4);
            float v0 = acc[0] + xv.x + bo4.x;
            float v1 = acc[1] + xv.y + bo4.y;
            float v2 = acc[2] + xv.z + bo4.z;
            float v3 = acc[3] + xv.w + bo4.w;
            x1res[m][0] = v0; x1res[m][1] = v1; x1res[m][2] = v2; x1res[m][3] = v3;
            st_b64(bufV + t * PIT + w * 16 + quad * 4, pk2(v0, v1), pk2(v2, v3));
        }
    }
    __syncthreads();

    // ---------------- P4: LN2(x1 in bufV) -> h2 into bufK ------------------
    {
        const int row = tid >> 2, part = tid & 3;
        const u16* src = bufV + row * PIT + part * 32;
        float v[32];
        float s = 0.f, s2 = 0.f;
        #pragma unroll
        for (int i = 0; i < 4; i++) {
            uint4 u = *reinterpret_cast<const uint4*>(src + i * 8);
            u32 arr[4] = {u.x, u.y, u.z, u.w};
            #pragma unroll
            for (int j = 0; j < 4; j++) {
                float f0 = __uint_as_float((arr[j] & 0xffffu) << 16);
                float f1 = __uint_as_float(arr[j] & 0xffff0000u);
                v[i * 8 + 2 * j] = f0; v[i * 8 + 2 * j + 1] = f1;
                s += f0 + f1; s2 += f0 * f0 + f1 * f1;
            }
        }
        s  += __shfl_xor(s, 1);  s2 += __shfl_xor(s2, 1);
        s  += __shfl_xor(s, 2);  s2 += __shfl_xor(s2, 2);
        float mean = s * (1.f / 128.f);
        float var  = fmaxf(s2 * (1.f / 128.f) - mean * mean, 0.f);
        float rstd = rsqrtf(var + 1e-5f);
        u16* dst = bufK + row * PIT + part * 32;
        #pragma unroll
        for (int i = 0; i < 4; i++) {
            u32 o4[4];
            #pragma unroll
            for (int j = 0; j < 4; j++) {
                int c = part * 32 + i * 8 + 2 * j;
                float r0 = (v[i * 8 + 2 * j]     - mean) * rstd * ln2g[c]     + ln2b[c];
                float r1 = (v[i * 8 + 2 * j + 1] - mean) * rstd * ln2g[c + 1] + ln2b[c + 1];
                o4[j] = (u32)f2b(r0) | ((u32)f2b(r1) << 16);
            }
            uint4 pk; pk.x = o4[0]; pk.y = o4[1]; pk.z = o4[2]; pk.w = o4[3];
            *reinterpret_cast<uint4*>(dst + i * 8) = pk;
        }
    }
    __syncthreads();

    // ---------------- P5: FF (swapped); G single-buffered in bufV ----------
    f32x4 oacc[8];
    #pragma unroll
    for (int m = 0; m < 8; m++) oacc[m] = f32x4{0, 0, 0, 0};

    #pragma unroll 1
    for (int fc = 0; fc < 4; fc++) {
        const int fbase = fc * 128;
        // G = relu(h2 @ W1c^T + b1): lane gets (f = w16+quad*4+r, t = m16+lq)
        bf16x8 w1a[4];
        #pragma unroll
        for (int ks = 0; ks < 4; ks++)
            w1a[ks] = ldfrag(w1 + (fbase + w * 16 + lq) * DDIM + ks * 32 + quad * 8);
        const float4 b14 = *reinterpret_cast<const float4*>(b1 + fbase + w * 16 + quad * 4);
        #pragma unroll
        for (int m = 0; m < 8; m++) {
            f32x4 acc = {0, 0, 0, 0};
            #pragma unroll
            for (int ks = 0; ks < 4; ks++) {
                bf16x8 hb = ldfrag(bufK + (m * 16 + lq) * PIT + ks * 32 + quad * 8);
                acc = mfma16(w1a[ks], hb, acc);
            }
            int t = m * 16 + lq;
            float g0 = fmaxf(acc[0] + b14.x, 0.f);
            float g1 = fmaxf(acc[1] + b14.y, 0.f);
            float g2 = fmaxf(acc[2] + b14.z, 0.f);
            float g3 = fmaxf(acc[3] + b14.w, 0.f);
            st_b64(bufV + t * PIT + w * 16 + quad * 4, pk2(g0, g1), pk2(g2, g3));
        }
        __syncthreads();   // G_fc writes visible
        // oacc += W2c @ G^T
        bf16x8 w2a[4];
        #pragma unroll
        for (int ks = 0; ks < 4; ks++)
            w2a[ks] = ldfrag(w2 + (w * 16 + lq) * FFD + fbase + ks * 32 + quad * 8);
        #pragma unroll
        for (int m = 0; m < 8; m++) {
            #pragma unroll
            for (int ks = 0; ks < 4; ks++) {
                bf16x8 gb = ldfrag(bufV + (m * 16 + lq) * PIT + ks * 32 + quad * 8);
                oacc[m] = mfma16(w2a[ks], gb, oacc[m]);
            }
        }
        if (fc < 3) __syncthreads();   // G_fc reads done before next write
    }

    // ---------------- P6: out = x1 + ff + b2 (float4 stores) ---------------
    {
        const float4 b24 = *reinterpret_cast<const float4*>(b2 + w * 16 + quad * 4);
        float* ob = out + (size_t)b * (TT * DDIM);
        #pragma unroll
        for (int m = 0; m < 8; m++) {
            int t = m * 16 + lq;
            float4 o;
            o.x = oacc[m][0] + x1res[m][0] + b24.x;
            o.y = oacc[m][1] + x1res[m][1] + b24.y;
            o.z = oacc[m][2] + x1res[m][2] + b24.z;
            o.w = oacc[m][3] + x1res[m][3] + b24.w;
            *reinterpret_cast<float4*>(ob + t * DDIM + w * 16 + quad * 4) = o;
        }
    }
}

extern "C" void kernel_launch(void* const* d_in, const int* in_sizes, int n_in,
                              void* d_out, int out_size, void* d_ws, size_t ws_size,
                              hipStream_t stream) {
    const float* x    = (const float*)d_in[0];
    const float* ln1g = (const float*)d_in[1];
    const float* ln1b = (const float*)d_in[2];
    const float* Wq   = (const float*)d_in[3];
    const float* Wk   = (const float*)d_in[4];
    const float* Wv   = (const float*)d_in[5];
    const float* Wo   = (const float*)d_in[6];
    const float* bo   = (const float*)d_in[7];
    const float* ln2g = (const float*)d_in[8];
    const float* ln2b = (const float*)d_in[9];
    const float* W1   = (const float*)d_in[10];
    const float* b1   = (const float*)d_in[11];
    const float* W2   = (const float*)d_in[12];
    const float* b2   = (const float*)d_in[13];
    float* out = (float*)d_out;
    u16* wbf = (u16*)d_ws;   // needs WTOT*2 = 393,216 B of workspace

    wprep<<<dim3((WTOT / 8 + 255) / 256), dim3(256), 0, stream>>>(
        Wq, Wk, Wv, Wo, W1, W2, wbf);

    const int nblocks = in_sizes[0] / (TT * DDIM);   // B = 1024
    tblock_kernel<<<dim3(nblocks), dim3(512), 0, stream>>>(
        x, ln1g, ln1b, wbf, bo, ln2g, ln2b, b1, b2, out);
}

// Round 9
// 283.585 us; speedup vs baseline: 1.2457x; 1.2457x over previous
//
#include <hip/hip_runtime.h>
#include <hip/hip_bf16.h>

// TransformerBlock fused kernel for MI355X (gfx950) — v8: v6.1 + bf16 weights
// + in-register P repack + x1/oacc merge.
// Shapes: B=1024, T=128, D=128, H=4, HD=32, FF=512.
// One block per batch element; 512 threads = 8 waves. LDS 139,264 B (1 block/CU
// accepted: unified VGPR+AGPR >128 caps residency at 8 waves/CU regardless —
// proven by v2.1/v3/v4/v7 occupancy attempts).
//
// Changes vs v6.1 (217.5 us):
//  1. Weights pre-converted to bf16 in d_ws by wprep (validated in v7): each
//     weight frag = one 16B load, no f32->bf16 VALU; Wq pre-scaled by
//     SCALE*log2e (no per-score multiply in softmax).
//  2. P2: P never touches LDS — quad_collect_pk (verified v3/v4) repacks the
//     unnormalized exp C-layout quarters into PV B-frags in-register. The 4
//     per-head s_waitcnt lgkmcnt(0) full-drain fences are GONE.
//  3. P3 initializes oacc with x1 (+x+bo); P5 W2 accumulates on top
//     (identical lane layout, verified); x1res eliminated (-32 regs).
// Everything else identical to v6.1: swapped GEMMs w/ b64 stores, barrier-free
// head loop on per-wave rows, LN2 via bufC round-trip, FF ping-pong A/B.
// MFMA 16x16x32 bf16. A-frag: A[m=lane&15][k=quad*8+j]; B-frag:
// B[k=quad*8+j][n=lane&15]; C/D: col=lane&15 (B n-dim), row=quad*4+reg (A m-dim).

typedef short bf16x8 __attribute__((ext_vector_type(8)));   // 8 bf16 in 4 VGPRs
typedef float f32x4  __attribute__((ext_vector_type(4)));
typedef unsigned short u16;
typedef unsigned int   u32;

#define TT   128
#define DDIM 128
#define FFD  512
#define PIT  136   // LDS row pitch (bf16): 272 B -> rows 16B-aligned

// ws layout (u16 element offsets) for bf16 weight copies
#define OWQ 0
#define OWK 16384
#define OWV 32768
#define OWO 49152
#define OW1 65536
#define OW2 131072
#define WTOT 196608

// SCALE * log2(e), folded into Wq at prep time. SCALE = 128^-0.5.
#define QSC 0.12751744f

#if defined(__has_builtin)
#if __has_builtin(__builtin_amdgcn_exp2f)
#define EXP2F(x) __builtin_amdgcn_exp2f(x)
#else
#define EXP2F(x) exp2f(x)
#endif
#else
#define EXP2F(x) exp2f(x)
#endif

__device__ __forceinline__ u16 f2b(float f) {
    __hip_bfloat16 h = __float2bfloat16(f);   // RNE
    return __builtin_bit_cast(u16, h);
}
__device__ __forceinline__ u32 pk2(float x, float y) {
    return (u32)f2b(x) | ((u32)f2b(y) << 16);
}
__device__ __forceinline__ void st_b64(u16* p, u32 lo, u32 hi) {  // 8B-aligned
    uint2 v; v.x = lo; v.y = hi;
    *reinterpret_cast<uint2*>(p) = v;
}
__device__ __forceinline__ bf16x8 ldfrag(const u16* p) {  // LDS/global, 16B-aligned
    return __builtin_bit_cast(bf16x8, *reinterpret_cast<const uint4*>(p));
}
__device__ __forceinline__ f32x4 mfma16(bf16x8 a, bf16x8 b, f32x4 c) {
    return __builtin_amdgcn_mfma_f32_16x16x32_bf16(a, b, c, 0, 0, 0);
}

// Cross-quad repack (verified in v3/v4 runs): pkv[i][d0] =
// pack(V[row][i*16+quad*4+2*d0], V[row][i*16+quad*4+2*d0+1]) (C-layout columns
// of this lane's row); output fr[g][j] = bf16(V[row][g*32+quad*8+j]) (A/B-frag).
__device__ __forceinline__ void quad_collect_pk(const u32 (&pkv)[8][2],
                                                bf16x8 (&fr)[4], int lane) {
    const int srcA = (lane & 15) + ((lane & 16) << 1);  // lq + 32*l4'
    const int srcB = srcA + 16;
    const bool hi = (lane & 32) != 0;                   // l5'
    #pragma unroll
    for (int g = 0; g < 4; g++) {
        u32 D00 = pkv[2*g][0],     D01 = pkv[2*g][1];
        u32 D10 = pkv[2*g + 1][0], D11 = pkv[2*g + 1][1];
        u32 a00 = (u32)__shfl((int)D00, srcA);
        u32 a10 = (u32)__shfl((int)D10, srcA);
        u32 a01 = (u32)__shfl((int)D01, srcA);
        u32 a11 = (u32)__shfl((int)D11, srcA);
        u32 b00 = (u32)__shfl((int)D00, srcB);
        u32 b10 = (u32)__shfl((int)D10, srcB);
        u32 b01 = (u32)__shfl((int)D01, srcB);
        u32 b11 = (u32)__shfl((int)D11, srcB);
        uint4 q;
        q.x = hi ? a10 : a00;
        q.y = hi ? a11 : a01;
        q.z = hi ? b10 : b00;
        q.w = hi ? b11 : b01;
        fr[g] = __builtin_bit_cast(bf16x8, q);
    }
}

// Weight prep: f32 -> bf16 copies into workspace (one tiny dispatch, ~3 us).
// Wq additionally scaled by QSC (folds softmax scale + log2e into Q).
__global__ __launch_bounds__(256) void wprep(
    const float* __restrict__ wq, const float* __restrict__ wk,
    const float* __restrict__ wv, const float* __restrict__ wo,
    const float* __restrict__ w1, const float* __restrict__ w2,
    u16* __restrict__ dst)
{
    int i = (blockIdx.x * 256 + threadIdx.x) * 8;
    if (i >= WTOT) return;
    const float* s; int off; float sc = 1.0f;
    if      (i < OWK) { s = wq; off = i - OWQ; sc = QSC; }
    else if (i < OWV) { s = wk; off = i - OWK; }
    else if (i < OWO) { s = wv; off = i - OWV; }
    else if (i < OW1) { s = wo; off = i - OWO; }
    else if (i < OW2) { s = w1; off = i - OW1; }
    else              { s = w2; off = i - OW2; }
    float4 a = *reinterpret_cast<const float4*>(s + off);
    float4 b = *reinterpret_cast<const float4*>(s + off + 4);
    uint4 o;
    o.x = pk2(a.x * sc, a.y * sc); o.y = pk2(a.z * sc, a.w * sc);
    o.z = pk2(b.x * sc, b.y * sc); o.w = pk2(b.z * sc, b.w * sc);
    *reinterpret_cast<uint4*>(dst + i) = o;
}

__global__ __launch_bounds__(512, 2) void tblock_kernel(
    const float* __restrict__ x,
    const float* __restrict__ ln1g, const float* __restrict__ ln1b,
    const u16*  __restrict__ wbf,
    const float* __restrict__ bo,
    const float* __restrict__ ln2g, const float* __restrict__ ln2b,
    const float* __restrict__ b1,   const float* __restrict__ b2,
    float* __restrict__ out)
{
    __shared__ __align__(16) u16 sm[4 * TT * PIT];
    u16* bufA = sm;                   // hs(LN1) -> G (fc even)
    u16* bufB = sm + 1 * TT * PIT;    // Q -> attn (per-wave rows) -> G (fc odd)
    u16* bufC = sm + 2 * TT * PIT;    // K -> x1 (bf16 for LN2)
    u16* bufD = sm + 3 * TT * PIT;    // Vt -> h2 (LN2)

    const int b    = blockIdx.x;
    const int tid  = threadIdx.x;
    const int w    = tid >> 6;     // wave id 0..7
    const int l    = tid & 63;
    const int lq   = l & 15;
    const int quad = l >> 4;
    const int trow = w * 16 + lq;  // this lane's token row (wave-private tile)
    const float* xb = x + (size_t)b * (TT * DDIM);

    const u16* wq = wbf + OWQ;
    const u16* wk = wbf + OWK;
    const u16* wv = wbf + OWV;
    const u16* wo = wbf + OWO;
    const u16* w1 = wbf + OW1;
    const u16* w2 = wbf + OW2;

    // ---------------- P0: LN1(x) -> bufA (bf16) ----------------
    {
        const int row = tid >> 2, part = tid & 3;
        const float* src = xb + row * DDIM + part * 32;
        float v[32];
        float s = 0.f, s2 = 0.f;
        #pragma unroll
        for (int i = 0; i < 8; i++) {
            float4 u = *reinterpret_cast<const float4*>(src + i * 4);
            v[i * 4 + 0] = u.x; v[i * 4 + 1] = u.y;
            v[i * 4 + 2] = u.z; v[i * 4 + 3] = u.w;
            s  += u.x + u.y + u.z + u.w;
            s2 += u.x * u.x + u.y * u.y + u.z * u.z + u.w * u.w;
        }
        s  += __shfl_xor(s, 1);  s2 += __shfl_xor(s2, 1);
        s  += __shfl_xor(s, 2);  s2 += __shfl_xor(s2, 2);
        float mean = s * (1.f / 128.f);
        float var  = fmaxf(s2 * (1.f / 128.f) - mean * mean, 0.f);
        float rstd = rsqrtf(var + 1e-5f);
        u16* dst = bufA + row * PIT + part * 32;
        #pragma unroll
        for (int i = 0; i < 4; i++) {
            u32 o4[4];
            #pragma unroll
            for (int j = 0; j < 4; j++) {
                int c = part * 32 + i * 8 + 2 * j;
                float r0 = (v[i * 8 + 2 * j]     - mean) * rstd * ln1g[c]     + ln1b[c];
                float r1 = (v[i * 8 + 2 * j + 1] - mean) * rstd * ln1g[c + 1] + ln1b[c + 1];
                o4[j] = (u32)f2b(r0) | ((u32)f2b(r1) << 16);
            }
            uint4 pk; pk.x = o4[0]; pk.y = o4[1]; pk.z = o4[2]; pk.w = o4[3];
            *reinterpret_cast<uint4*>(dst + i * 8) = pk;
        }
    }
    __syncthreads();

    // ---------------- P1: Q -> bufB, K -> bufC (swapped, b64); Vt -> bufD ----
    {
        bf16x8 aq[4], ak[4];
        #pragma unroll
        for (int ks = 0; ks < 4; ks++) {
            aq[ks] = ldfrag(wq + (w * 16 + lq) * DDIM + ks * 32 + quad * 8);
            ak[ks] = ldfrag(wk + (w * 16 + lq) * DDIM + ks * 32 + quad * 8);
        }
        #pragma unroll
        for (int m = 0; m < 8; m++) {
            f32x4 accq = {0, 0, 0, 0}, acck = {0, 0, 0, 0};
            #pragma unroll
            for (int ks = 0; ks < 4; ks++) {
                bf16x8 bh = ldfrag(bufA + (m * 16 + lq) * PIT + ks * 32 + quad * 8);
                accq = mfma16(aq[ks], bh, accq);
                acck = mfma16(ak[ks], bh, acck);
            }
            int t = m * 16 + lq;
            st_b64(bufB + t * PIT + w * 16 + quad * 4, pk2(accq[0], accq[1]), pk2(accq[2], accq[3]));
            st_b64(bufC + t * PIT + w * 16 + quad * 4, pk2(acck[0], acck[1]), pk2(acck[2], acck[3]));
        }
        // Vt = Wv @ hs^T: lane gets (o=w16+quad*4+r, t=n*16+lq) -> b16 scatter.
        bf16x8 av[4];
        #pragma unroll
        for (int ks = 0; ks < 4; ks++)
            av[ks] = ldfrag(wv + (w * 16 + lq) * DDIM + ks * 32 + quad * 8);
        #pragma unroll
        for (int n = 0; n < 8; n++) {
            f32x4 acc = {0, 0, 0, 0};
            #pragma unroll
            for (int ks = 0; ks < 4; ks++) {
                bf16x8 bh = ldfrag(bufA + (n * 16 + lq) * PIT + ks * 32 + quad * 8);
                acc = mfma16(av[ks], bh, acc);
            }
            #pragma unroll
            for (int r = 0; r < 4; r++) {
                int o = w * 16 + quad * 4 + r;
                bufD[o * PIT + n * 16 + lq] = f2b(acc[r]);
            }
        }
    }
    __syncthreads();

    // ---------------- P2: attention, barrier-free, P in-register -----------
    // Swapped S^T = mfma(K-frag, Q-frag): lane (lq,quad) holds the QUARTER of
    // score row trow at s = n*16+quad*4+r; full row spans the 4 quads.
    #pragma unroll 1
    for (int h = 0; h < 4; h++) {
        bf16x8 qb = ldfrag(bufB + trow * PIT + h * 32 + quad * 8);
        float p[8][4];
        #pragma unroll
        for (int n = 0; n < 8; n++) {
            bf16x8 ka = ldfrag(bufC + (n * 16 + lq) * PIT + h * 32 + quad * 8);
            f32x4 s4 = mfma16(ka, qb, f32x4{0, 0, 0, 0});
            #pragma unroll
            for (int r = 0; r < 4; r++) p[n][r] = s4[r];
        }
        // causal softmax (exp2 domain, scale pre-folded into Wq, norm deferred)
        float mx = -3.0e38f;
        #pragma unroll
        for (int n = 0; n < 8; n++) {
            #pragma unroll
            for (int r = 0; r < 4; r++) {
                int sc = n * 16 + quad * 4 + r;
                mx = (sc <= trow) ? fmaxf(mx, p[n][r]) : mx;
            }
        }
        mx = fmaxf(mx, __shfl_xor(mx, 16));
        mx = fmaxf(mx, __shfl_xor(mx, 32));   // full-row max
        float sum = 0.f;
        u32 ppk[8][2];   // unnormalized exp, packed bf16 pairs
        #pragma unroll
        for (int n = 0; n < 8; n++) {
            int sc = n * 16 + quad * 4;
            float e0 = (sc     <= trow) ? EXP2F(p[n][0] - mx) : 0.f;
            float e1 = (sc + 1 <= trow) ? EXP2F(p[n][1] - mx) : 0.f;
            float e2 = (sc + 2 <= trow) ? EXP2F(p[n][2] - mx) : 0.f;
            float e3 = (sc + 3 <= trow) ? EXP2F(p[n][3] - mx) : 0.f;
            sum += e0 + e1 + e2 + e3;
            ppk[n][0] = pk2(e0, e1);
            ppk[n][1] = pk2(e2, e3);
        }
        sum += __shfl_xor(sum, 16);
        sum += __shfl_xor(sum, 32);           // full-row sum
        float inv = 1.f / sum;   // sum >= 1 (max entry contributes exp2(0)=1)
        // P -> B-frags fully in-register (no LDS, no lgkm fence)
        bf16x8 pfr[4];
        quad_collect_pk(ppk, pfr, l);
        // Swapped PV: attn^T = mfma(A=Vt, B=P); output rows n=lq = trow.
        f32x4 o0 = {0, 0, 0, 0}, o1 = {0, 0, 0, 0};
        #pragma unroll
        for (int ks = 0; ks < 4; ks++) {
            bf16x8 va0 = ldfrag(bufD + (h * 32 + lq) * PIT + ks * 32 + quad * 8);
            bf16x8 va1 = ldfrag(bufD + (h * 32 + 16 + lq) * PIT + ks * 32 + quad * 8);
            o0 = mfma16(va0, pfr[ks], o0);
            o1 = mfma16(va1, pfr[ks], o1);
        }
        #pragma unroll
        for (int r = 0; r < 4; r++) { o0[r] *= inv; o1[r] *= inv; }
        // attn into Q's head-h columns (wave-private rows, Q_h consumed)
        st_b64(bufB + trow * PIT + h * 32 + quad * 4,      pk2(o0[0], o0[1]), pk2(o0[2], o0[3]));
        st_b64(bufB + trow * PIT + h * 32 + 16 + quad * 4, pk2(o1[0], o1[1]), pk2(o1[2], o1[3]));
    }
    __syncthreads();   // attn concat complete across all waves

    // ---------------- P3: oacc = x1 = x + attn @ Wo^T + bo -----------------
    // oacc[m] layout [d=w*16+quad*4+r][t=m*16+lq] == P5 W2-accumulator layout;
    // FF partials accumulate on top, P6 adds b2 only.
    f32x4 oacc[8];
    {
        bf16x8 woa[4];
        #pragma unroll
        for (int ks = 0; ks < 4; ks++)
            woa[ks] = ldfrag(wo + (w * 16 + lq) * DDIM + ks * 32 + quad * 8);
        const float4 bo4 = *reinterpret_cast<const float4*>(bo + w * 16 + quad * 4);
        #pragma unroll
        for (int m = 0; m < 8; m++) {
            f32x4 acc = {0, 0, 0, 0};
            #pragma unroll
            for (int ks = 0; ks < 4; ks++) {
                bf16x8 ab = ldfrag(bufB + (m * 16 + lq) * PIT + ks * 32 + quad * 8);
                acc = mfma16(woa[ks], ab, acc);
            }
            int t = m * 16 + lq;
            const float4 xv = *reinterpret_cast<const float4*>(xb + t * DDIM + w * 16 + quad * 4);
            oacc[m][0] = acc[0] + xv.x + bo4.x;
            oacc[m][1] = acc[1] + xv.y + bo4.y;
            oacc[m][2] = acc[2] + xv.z + bo4.z;
            oacc[m][3] = acc[3] + xv.w + bo4.w;
            st_b64(bufC + t * PIT + w * 16 + quad * 4,
                   pk2(oacc[m][0], oacc[m][1]), pk2(oacc[m][2], oacc[m][3]));
        }
    }
    __syncthreads();

    // ---------------- P4: LN2(x1 in bufC) -> bufD (bf16) -------------------
    {
        const int row = tid >> 2, part = tid & 3;
        const u16* src = bufC + row * PIT + part * 32;
        float v[32];
        float s = 0.f, s2 = 0.f;
        #pragma unroll
        for (int i = 0; i < 4; i++) {
            uint4 u = *reinterpret_cast<const uint4*>(src + i * 8);
            u32 arr[4] = {u.x, u.y, u.z, u.w};
            #pragma unroll
            for (int j = 0; j < 4; j++) {
                float f0 = __uint_as_float((arr[j] & 0xffffu) << 16);
                float f1 = __uint_as_float(arr[j] & 0xffff0000u);
                v[i * 8 + 2 * j] = f0; v[i * 8 + 2 * j + 1] = f1;
                s += f0 + f1; s2 += f0 * f0 + f1 * f1;
            }
        }
        s  += __shfl_xor(s, 1);  s2 += __shfl_xor(s2, 1);
        s  += __shfl_xor(s, 2);  s2 += __shfl_xor(s2, 2);
        float mean = s * (1.f / 128.f);
        float var  = fmaxf(s2 * (1.f / 128.f) - mean * mean, 0.f);
        float rstd = rsqrtf(var + 1e-5f);
        u16* dst = bufD + row * PIT + part * 32;
        #pragma unroll
        for (int i = 0; i < 4; i++) {
            u32 o4[4];
            #pragma unroll
            for (int j = 0; j < 4; j++) {
                int c = part * 32 + i * 8 + 2 * j;
                float r0 = (v[i * 8 + 2 * j]     - mean) * rstd * ln2g[c]     + ln2b[c];
                float r1 = (v[i * 8 + 2 * j + 1] - mean) * rstd * ln2g[c + 1] + ln2b[c + 1];
                o4[j] = (u32)f2b(r0) | ((u32)f2b(r1) << 16);
            }
            uint4 pk; pk.x = o4[0]; pk.y = o4[1]; pk.z = o4[2]; pk.w = o4[3];
            *reinterpret_cast<uint4*>(dst + i * 8) = pk;
        }
    }
    __syncthreads();

    // ---------------- P5: FF (swapped); G ping-pongs A/B; oacc += ff -------
    #pragma unroll 1
    for (int fc = 0; fc < 4; fc++) {
        const int fbase = fc * 128;
        u16* gbuf = (fc & 1) ? bufB : bufA;   // both dead; WAR-free swap
        // G = relu(h2 @ W1c^T + b1): lane gets (f = w16+quad*4+r, t = m16+lq)
        bf16x8 w1a[4];
        #pragma unroll
        for (int ks = 0; ks < 4; ks++)
            w1a[ks] = ldfrag(w1 + (fbase + w * 16 + lq) * DDIM + ks * 32 + quad * 8);
        const float4 b14 = *reinterpret_cast<const float4*>(b1 + fbase + w * 16 + quad * 4);
        #pragma unroll
        for (int m = 0; m < 8; m++) {
            f32x4 acc = {0, 0, 0, 0};
            #pragma unroll
            for (int ks = 0; ks < 4; ks++) {
                bf16x8 hb = ldfrag(bufD + (m * 16 + lq) * PIT + ks * 32 + quad * 8);
                acc = mfma16(w1a[ks], hb, acc);
            }
            int t = m * 16 + lq;
            float g0 = fmaxf(acc[0] + b14.x, 0.f);
            float g1 = fmaxf(acc[1] + b14.y, 0.f);
            float g2 = fmaxf(acc[2] + b14.z, 0.f);
            float g3 = fmaxf(acc[3] + b14.w, 0.f);
            st_b64(gbuf + t * PIT + w * 16 + quad * 4, pk2(g0, g1), pk2(g2, g3));
        }
        __syncthreads();   // G_fc complete (cross-wave read follows)
        // oacc += W2c @ G^T: lane (d = w16+quad*4+r, t = m16+lq)
        bf16x8 w2a[4];
        #pragma unroll
        for (int ks = 0; ks < 4; ks++)
            w2a[ks] = ldfrag(w2 + (w * 16 + lq) * FFD + fbase + ks * 32 + quad * 8);
        #pragma unroll
        for (int m = 0; m < 8; m++) {
            #pragma unroll
            for (int ks = 0; ks < 4; ks++) {
                bf16x8 gb = ldfrag(gbuf + (m * 16 + lq) * PIT + ks * 32 + quad * 8);
                oacc[m] = mfma16(w2a[ks], gb, oacc[m]);
            }
        }
        // no trailing barrier: next fc writes the OTHER buffer
    }

    // ---------------- P6: out = oacc + b2 (float4 stores) ------------------
    {
        const float4 b24 = *reinterpret_cast<const float4*>(b2 + w * 16 + quad * 4);
        float* ob = out + (size_t)b * (TT * DDIM);
        #pragma unroll
        for (int m = 0; m < 8; m++) {
            int t = m * 16 + lq;
            float4 o;
            o.x = oacc[m][0] + b24.x;
            o.y = oacc[m][1] + b24.y;
            o.z = oacc[m][2] + b24.z;
            o.w = oacc[m][3] + b24.w;
            *reinterpret_cast<float4*>(ob + t * DDIM + w * 16 + quad * 4) = o;
        }
    }
}

extern "C" void kernel_launch(void* const* d_in, const int* in_sizes, int n_in,
                              void* d_out, int out_size, void* d_ws, size_t ws_size,
                              hipStream_t stream) {
    const float* x    = (const float*)d_in[0];
    const float* ln1g = (const float*)d_in[1];
    const float* ln1b = (const float*)d_in[2];
    const float* Wq   = (const float*)d_in[3];
    const float* Wk   = (const float*)d_in[4];
    const float* Wv   = (const float*)d_in[5];
    const float* Wo   = (const float*)d_in[6];
    const float* bo   = (const float*)d_in[7];
    const float* ln2g = (const float*)d_in[8];
    const float* ln2b = (const float*)d_in[9];
    const float* W1   = (const float*)d_in[10];
    const float* b1   = (const float*)d_in[11];
    const float* W2   = (const float*)d_in[12];
    const float* b2   = (const float*)d_in[13];
    float* out = (float*)d_out;
    u16* wbf = (u16*)d_ws;   // needs WTOT*2 = 393,216 B (validated in v7)

    wprep<<<dim3((WTOT / 8 + 255) / 256), dim3(256), 0, stream>>>(
        Wq, Wk, Wv, Wo, W1, W2, wbf);

    const int nblocks = in_sizes[0] / (TT * DDIM);   // B = 1024
    tblock_kernel<<<dim3(nblocks), dim3(512), 0, stream>>>(
        x, ln1g, ln1b, wbf, bo, ln2g, ln2b, b1, b2, out);
}